// Round 1
// baseline (628.677 us; speedup 1.0000x reference)
//
#include <hip/hip_runtime.h>
#include <math.h>

#define MTOT 65536   // B*T
#define DD   128
#define KK   1024
#define BETA 0.25f

// ---------------- K1: codebook norms + zero the loss accumulator ------------
__global__ void k_norms(const float* __restrict__ e,
                        float* __restrict__ ne, float* __restrict__ inv_ne,
                        float* __restrict__ loss) {
    int gwave = (blockIdx.x * 256 + threadIdx.x) >> 6;   // 64 waves total
    int lane  = threadIdx.x & 63;
    for (int k = gwave; k < KK; k += 64) {
        float2 v = ((const float2*)(e + (size_t)k * DD))[lane];
        float s = v.x * v.x + v.y * v.y;
        #pragma unroll
        for (int off = 32; off; off >>= 1) s += __shfl_down(s, off, 64);
        if (lane == 0) { ne[k] = s; inv_ne[k] = 1.0f / sqrtf(s); }
    }
    if (blockIdx.x == 0 && threadIdx.x == 0) *loss = 0.0f;
}

// ---------------- K2: fused GEMM + similarity + argmin ----------------------
#define MT 64    // rows per block
#define NT 64    // cols per chunk
#define AS 132   // padded LDS stride (keeps 16B alignment, breaks bank aliasing)

__launch_bounds__(256, 2)
__global__ void k_main(const float* __restrict__ z, const float* __restrict__ e,
                       const float* __restrict__ ne, const float* __restrict__ inv_ne,
                       float* __restrict__ sim, int* __restrict__ ids_out) {
    __shared__ float A[MT * AS];
    __shared__ float Bs[NT * AS];
    __shared__ float nzs[MT], inzs[MT];
    __shared__ float redv[MT][16];
    __shared__ int   redi[MT][16];

    const int t  = threadIdx.x;      // 0..255
    const int tx = t & 15, ty = t >> 4;
    const int r0 = blockIdx.x * MT;

    // stage A tile (64 x 128), coalesced float4
    #pragma unroll
    for (int it = 0; it < 8; ++it) {
        int lin = it * 256 + t;
        int row = lin >> 5, dg = lin & 31;
        float4 v = ((const float4*)(z + (size_t)(r0 + row) * DD))[dg];
        *(float4*)&A[row * AS + dg * 4] = v;
    }
    __syncthreads();

    // per-row |z|^2 (wave 0 only; once per block)
    if (t < MT) {
        float s = 0.f;
        #pragma unroll
        for (int dg = 0; dg < 32; ++dg) {
            float4 v = *(const float4*)&A[t * AS + dg * 4];
            s += v.x * v.x + v.y * v.y + v.z * v.z + v.w * v.w;
        }
        nzs[t]  = s;
        inzs[t] = 1.0f / sqrtf(s);
    }
    __syncthreads();

    float nzr[4], inzr[4];
    #pragma unroll
    for (int i = 0; i < 4; ++i) { nzr[i] = nzs[ty * 4 + i]; inzr[i] = inzs[ty * 4 + i]; }

    float bestv[4]; int besti[4];
    #pragma unroll
    for (int i = 0; i < 4; ++i) { bestv[i] = 3.4e38f; besti[i] = 0; }

    for (int ch = 0; ch < KK / NT; ++ch) {
        const int c0 = ch * NT;

        // prefetch this thread's column norms (L2-resident; hidden by d-loop)
        float nec[4], inec[4];
        #pragma unroll
        for (int j = 0; j < 4; ++j) {
            int c = c0 + tx + 16 * j;
            nec[j] = ne[c]; inec[j] = inv_ne[c];
        }

        __syncthreads();               // previous chunk done reading Bs
        #pragma unroll
        for (int it = 0; it < 8; ++it) {
            int lin = it * 256 + t;
            int code = lin >> 5, dg = lin & 31;
            float4 v = ((const float4*)(e + (size_t)(c0 + code) * DD))[dg];
            *(float4*)&Bs[code * AS + dg * 4] = v;
        }
        __syncthreads();

        float acc[4][4];
        #pragma unroll
        for (int i = 0; i < 4; ++i)
            #pragma unroll
            for (int j = 0; j < 4; ++j) acc[i][j] = 0.f;

        #pragma unroll 2
        for (int d = 0; d < DD; d += 4) {
            float4 a4[4], b4[4];
            #pragma unroll
            for (int i = 0; i < 4; ++i) a4[i] = *(const float4*)&A[(ty * 4 + i) * AS + d];
            #pragma unroll
            for (int j = 0; j < 4; ++j) b4[j] = *(const float4*)&Bs[(tx + 16 * j) * AS + d];
            #pragma unroll
            for (int i = 0; i < 4; ++i)
                #pragma unroll
                for (int j = 0; j < 4; ++j)
                    acc[i][j] += a4[i].x * b4[j].x + a4[i].y * b4[j].y
                               + a4[i].z * b4[j].z + a4[i].w * b4[j].w;
        }

        // epilogue: similarity write + argmin update (cols ascend with j -> first-occurrence tie-break)
        #pragma unroll
        for (int i = 0; i < 4; ++i) {
            float* srow = sim + (size_t)(r0 + ty * 4 + i) * KK + c0 + tx;
            #pragma unroll
            for (int j = 0; j < 4; ++j) {
                float dot = acc[i][j];
                srow[16 * j] = dot * inzr[i] * inec[j];
                float dist = nzr[i] + nec[j] - 2.0f * dot;
                if (dist < bestv[i]) { bestv[i] = dist; besti[i] = c0 + tx + 16 * j; }
            }
        }
    }

    // cross-thread argmin per row
    __syncthreads();
    #pragma unroll
    for (int i = 0; i < 4; ++i) { redv[ty * 4 + i][tx] = bestv[i]; redi[ty * 4 + i][tx] = besti[i]; }
    __syncthreads();
    if (t < MT) {
        float bv = redv[t][0]; int bi = redi[t][0];
        #pragma unroll
        for (int x = 1; x < 16; ++x) {
            float v = redv[t][x]; int ii = redi[t][x];
            if (v < bv || (v == bv && ii < bi)) { bv = v; bi = ii; }
        }
        ids_out[r0 + t] = bi;
    }
}

// ---------------- K3: gather z_q, ids->float, loss --------------------------
__global__ void k_finish(const float* __restrict__ z, const float* __restrict__ e,
                         float* __restrict__ zq, float* __restrict__ ids_f,
                         float* __restrict__ loss) {
    const int lane = threadIdx.x & 63;
    const int wv   = threadIdx.x >> 6;
    const int base = blockIdx.x * 256 + wv * 64;     // 64 rows per wave
    const int* ids_in = (const int*)ids_f;
    float wsum = 0.f;
    for (int rr = 0; rr < 64; ++rr) {
        int row = base + rr;
        int id  = ids_in[row];                       // read before float overwrite (same wave)
        float2 zv = ((const float2*)(z + (size_t)row * DD))[lane];
        float2 ev = ((const float2*)(e + (size_t)id  * DD))[lane];
        ((float2*)(zq + (size_t)row * DD))[lane] = ev;
        float dx = zv.x - ev.x, dy = zv.y - ev.y;
        float s = dx * dx + dy * dy;
        #pragma unroll
        for (int off = 32; off; off >>= 1) s += __shfl_down(s, off, 64);
        if (lane == 0) {
            wsum += sqrtf(s);
            ids_f[row] = (float)id;
        }
    }
    __shared__ float bs[4];
    if (lane == 0) bs[wv] = wsum;
    __syncthreads();
    if (threadIdx.x == 0)
        atomicAdd(loss, (bs[0] + bs[1] + bs[2] + bs[3]) * ((1.0f + BETA) / (float)MTOT));
}

// ---------------- launcher --------------------------------------------------
extern "C" void kernel_launch(void* const* d_in, const int* in_sizes, int n_in,
                              void* d_out, int out_size, void* d_ws, size_t ws_size,
                              hipStream_t stream) {
    const float* z = (const float*)d_in[0];   // z_e [16,4096,128]
    const float* e = (const float*)d_in[1];   // vecs_embedding [1024,128]
    float* out  = (float*)d_out;
    float* zq   = out;                                   // [MTOT*DD]
    float* sim  = out + (size_t)MTOT * DD;               // [MTOT*KK]
    float* idsf = sim + (size_t)MTOT * KK;               // [MTOT]
    float* loss = idsf + MTOT;                           // [1]

    // scratch: stash codebook norms in the z_q region (overwritten later by k_finish)
    float* ne     = zq;
    float* inv_ne = zq + KK;

    k_norms <<<16,        256, 0, stream>>>(e, ne, inv_ne, loss);
    k_main  <<<MTOT / MT, 256, 0, stream>>>(z, e, ne, inv_ne, sim, (int*)idsf);
    k_finish<<<MTOT / 256,256, 0, stream>>>(z, e, zq, idsf, loss);
}

// Round 2
// 537.987 us; speedup vs baseline: 1.1686x; 1.1686x over previous
//
#include <hip/hip_runtime.h>
#include <math.h>

#define MTOT 65536   // B*T
#define DD   128
#define KK   1024
#define BETA 0.25f
#define TM   64      // rows per k_main block
#define NCH  64      // codes per chunk
#define LSTR 136     // LDS row stride in bf16 (272 B: 16B-aligned, 2-way banks only)

typedef __attribute__((ext_vector_type(8))) short short8;
typedef __attribute__((ext_vector_type(4))) float float4v;

__device__ __forceinline__ unsigned bf16_rne(float x) {
    unsigned u = __float_as_uint(x);
    return (u + 0x7fffu + ((u >> 16) & 1u)) >> 16;
}

// --------- K0: codebook -> bf16 hi/lo (into z_q region) + norms + zero loss -
__global__ void k_norms(const float* __restrict__ e, ushort* __restrict__ bh,
                        float* __restrict__ nef, float* __restrict__ inef,
                        float* __restrict__ loss) {
    const int gw = blockIdx.x * 4 + (threadIdx.x >> 6);
    const int lane = threadIdx.x & 63;
    ushort* bl = bh + 131072;                 // lo part after hi part
    for (int code = gw; code < KK; code += 16) {
        float2 ev = ((const float2*)(e + (size_t)code * DD))[lane];
        unsigned h0 = bf16_rne(ev.x), h1 = bf16_rne(ev.y);
        float l0f = ev.x - __uint_as_float(h0 << 16);
        float l1f = ev.y - __uint_as_float(h1 << 16);
        ushort2 hv; hv.x = (ushort)h0; hv.y = (ushort)h1;
        ushort2 lv; lv.x = (ushort)bf16_rne(l0f); lv.y = (ushort)bf16_rne(l1f);
        ((ushort2*)(bh + code * 128))[lane] = hv;
        ((ushort2*)(bl + code * 128))[lane] = lv;
        float s = ev.x * ev.x + ev.y * ev.y;
        #pragma unroll
        for (int off = 32; off; off >>= 1) s += __shfl_down(s, off, 64);
        if (lane == 0) { nef[code] = s; inef[code] = 1.0f / sqrtf(s); }
    }
    if (blockIdx.x == 0 && threadIdx.x == 0) *loss = 0.0f;
}

// --------- K1: z_e -> bf16 hi/lo + |z|^2, stored in each row's OWN sim slot -
__global__ void k_prep(const float* __restrict__ z, float* __restrict__ sim) {
    const int lane = threadIdx.x & 63, w = threadIdx.x >> 6;
    const int rbase = blockIdx.x * 32 + w * 8;
    for (int i = 0; i < 8; ++i) {
        int row = rbase + i;
        float2 zv = ((const float2*)(z + (size_t)row * DD))[lane];
        unsigned h0 = bf16_rne(zv.x), h1 = bf16_rne(zv.y);
        float l0f = zv.x - __uint_as_float(h0 << 16);
        float l1f = zv.y - __uint_as_float(h1 << 16);
        ushort2 hv; hv.x = (ushort)h0; hv.y = (ushort)h1;
        ushort2 lv; lv.x = (ushort)bf16_rne(l0f); lv.y = (ushort)bf16_rne(l1f);
        ushort* srow = (ushort*)(sim + (size_t)row * KK);
        ((ushort2*)srow)[lane] = hv;          // bytes [0,256): hi
        ((ushort2*)(srow + 128))[lane] = lv;  // bytes [256,512): lo
        float s = zv.x * zv.x + zv.y * zv.y;
        #pragma unroll
        for (int off = 32; off; off >>= 1) s += __shfl_down(s, off, 64);
        if (lane == 0) {
            float* fr = sim + (size_t)row * KK;
            fr[128] = s;                      // |z|^2 at float idx 128
            fr[129] = 1.0f / sqrtf(s);        // 1/|z| at 129 (both read-before-overwrite)
        }
    }
}

// --------- K2: split-bf16 MFMA GEMM + sim write + top-2 candidate tracking --
__launch_bounds__(256, 2)
__global__ void k_main(const float* __restrict__ simA, float* __restrict__ sim,
                       const ushort* __restrict__ bpre,
                       const float* __restrict__ nef, const float* __restrict__ inef,
                       unsigned* __restrict__ cand) {
    __shared__ __align__(16) ushort Ah[TM * LSTR], Al[TM * LSTR];
    __shared__ __align__(16) ushort Bh[NCH * LSTR], Bl[NCH * LSTR];
    __shared__ float nzv[TM], inzv[TM];

    const int t = threadIdx.x;
    const int w = t >> 6, lane = t & 63, cl = lane & 15, q = lane >> 4;
    const int mh = (w & 1) * 32, nh = (w >> 1) * 32;
    const int r0 = blockIdx.x * TM;

    // stage A tile: 64 rows x (hi|lo) from the prepass data in sim's own rows
    #pragma unroll
    for (int i = 0; i < 8; ++i) {
        int slot = i * 256 + t;
        int row = slot >> 5, win = slot & 31, part = win >> 4, kb = win & 15;
        uint4 v = *(const uint4*)((const char*)simA + (size_t)(r0 + row) * KK * 4 + part * 256 + kb * 16);
        *(uint4*)((part ? Al : Ah) + row * LSTR + kb * 8) = v;
    }
    if (t < TM) {
        const float* fr = simA + (size_t)(r0 + t) * KK;
        nzv[t] = fr[128]; inzv[t] = fr[129];
    }
    __syncthreads();

    float nzr[8], inzr[8];
    #pragma unroll
    for (int mt = 0; mt < 2; ++mt)
        #pragma unroll
        for (int r = 0; r < 4; ++r) {
            int rl = mh + mt * 16 + q * 4 + r;
            nzr[mt * 4 + r] = nzv[rl]; inzr[mt * 4 + r] = inzv[rl];
        }

    float b1v[8], b2v[8]; int b1i[8], b2i[8];
    #pragma unroll
    for (int s = 0; s < 8; ++s) { b1v[s] = 3.4e38f; b2v[s] = 3.4e38f; b1i[s] = 0; b2i[s] = 0; }

    for (int ch = 0; ch < KK / NCH; ++ch) {
        const int c0 = ch * NCH;
        float nec[2], inec[2];
        #pragma unroll
        for (int nt = 0; nt < 2; ++nt) {
            int c = c0 + nh + nt * 16 + cl;
            nec[nt] = nef[c]; inec[nt] = inef[c];
        }
        __syncthreads();                      // prev chunk done reading B
        #pragma unroll
        for (int i = 0; i < 8; ++i) {
            int slot = i * 256 + t;
            int code = slot >> 5, win = slot & 31, part = win >> 4, kb = win & 15;
            uint4 v = *(const uint4*)((const char*)bpre + (size_t)part * 262144
                                      + (size_t)(c0 + code) * 256 + kb * 16);
            *(uint4*)((part ? Bl : Bh) + code * LSTR + kb * 8) = v;
        }
        __syncthreads();

        float4v acc[2][2];
        #pragma unroll
        for (int mt = 0; mt < 2; ++mt)
            #pragma unroll
            for (int nt = 0; nt < 2; ++nt) acc[mt][nt] = (float4v)(0.0f);

        // 3 passes: Ah*Bh + Ah*Bl + Al*Bh  (lo*lo dropped)
        #pragma unroll
        for (int p = 0; p < 3; ++p) {
            const ushort* Ap = (p == 2) ? Al : Ah;
            const ushort* Bp = (p == 1) ? Bl : Bh;
            #pragma unroll
            for (int s = 0; s < 4; ++s) {
                const int ko = s * 32 + q * 8;
                short8 a0 = *(const short8*)&Ap[(mh + cl) * LSTR + ko];
                short8 a1 = *(const short8*)&Ap[(mh + 16 + cl) * LSTR + ko];
                short8 bb0 = *(const short8*)&Bp[(nh + cl) * LSTR + ko];
                short8 bb1 = *(const short8*)&Bp[(nh + 16 + cl) * LSTR + ko];
                acc[0][0] = __builtin_amdgcn_mfma_f32_16x16x32_bf16(a0, bb0, acc[0][0], 0, 0, 0);
                acc[0][1] = __builtin_amdgcn_mfma_f32_16x16x32_bf16(a0, bb1, acc[0][1], 0, 0, 0);
                acc[1][0] = __builtin_amdgcn_mfma_f32_16x16x32_bf16(a1, bb0, acc[1][0], 0, 0, 0);
                acc[1][1] = __builtin_amdgcn_mfma_f32_16x16x32_bf16(a1, bb1, acc[1][1], 0, 0, 0);
            }
        }

        // epilogue: sim write + per-lane top-2 (cols ascend: nt inner)
        #pragma unroll
        for (int mt = 0; mt < 2; ++mt)
            #pragma unroll
            for (int r = 0; r < 4; ++r) {
                const int slot = mt * 4 + r;
                const size_t rowg = (size_t)(r0 + mh + mt * 16 + q * 4 + r);
                #pragma unroll
                for (int nt = 0; nt < 2; ++nt) {
                    float dot = acc[mt][nt][r];
                    int col = c0 + nh + nt * 16 + cl;
                    sim[rowg * KK + col] = dot * inzr[slot] * inec[nt];
                    float dist = fmaf(-2.0f, dot, nzr[slot] + nec[nt]);
                    if (dist < b1v[slot]) {
                        b2v[slot] = b1v[slot]; b2i[slot] = b1i[slot];
                        b1v[slot] = dist;      b1i[slot] = col;
                    } else if (dist < b2v[slot]) {
                        b2v[slot] = dist; b2i[slot] = col;
                    }
                }
            }
    }

    // cross-lane top-2 merge per row (reuse LDS: Ah as floats, Bh as ints)
    __syncthreads();
    float* redv = (float*)Ah;   // [64 rows][32 entries][2]
    int*   redi = (int*)Bh;
    #pragma unroll
    for (int mt = 0; mt < 2; ++mt)
        #pragma unroll
        for (int r = 0; r < 4; ++r) {
            int slot = mt * 4 + r;
            int rl = mh + mt * 16 + q * 4 + r;
            int ei = rl * 64 + ((w >> 1) * 16 + cl) * 2;
            redv[ei] = b1v[slot]; redv[ei + 1] = b2v[slot];
            redi[ei] = b1i[slot]; redi[ei + 1] = b2i[slot];
        }
    __syncthreads();
    if (t < TM) {
        float B1v = 3.4e38f, B2v = 3.4e38f; int B1i = 0x7fffffff, B2i = 0x7fffffff;
        for (int j = 0; j < 64; ++j) {
            float v = redv[t * 64 + j]; int ii = redi[t * 64 + j];
            if (v < B1v || (v == B1v && ii < B1i)) { B2v = B1v; B2i = B1i; B1v = v; B1i = ii; }
            else if (v < B2v || (v == B2v && ii < B2i)) { B2v = v; B2i = ii; }
        }
        cand[r0 + t] = (unsigned)B1i | ((unsigned)B2i << 16);
    }
}

// --------- K3: exact fp32 re-rank of top-2, z_q gather, ids->float, loss ----
__global__ void k_finish(const float* __restrict__ z, const float* __restrict__ e,
                         float* __restrict__ zq, float* __restrict__ idsf,
                         float* __restrict__ loss) {
    const int t = threadIdx.x, w = t >> 6, lane = t & 63;
    const int rbase = blockIdx.x * 64 + w * 16;
    float wsum = 0.0f;
    for (int i = 0; i < 16; ++i) {
        int row = rbase + i;
        unsigned pk = ((const unsigned*)idsf)[row];
        int c1 = (int)(pk & 0xffffu), c2 = (int)(pk >> 16);
        float2 zv = ((const float2*)(z + (size_t)row * DD))[lane];
        float2 e1 = ((const float2*)(e + (size_t)c1 * DD))[lane];
        float2 e2 = ((const float2*)(e + (size_t)c2 * DD))[lane];
        float v0 = zv.x * zv.x + zv.y * zv.y;   // |z|^2
        float v1 = zv.x * e1.x + zv.y * e1.y;   // z.e1
        float v2 = zv.x * e2.x + zv.y * e2.y;   // z.e2
        float v3 = e1.x * e1.x + e1.y * e1.y;   // |e1|^2
        float v4 = e2.x * e2.x + e2.y * e2.y;   // |e2|^2
        #pragma unroll
        for (int off = 32; off; off >>= 1) {
            v0 += __shfl_down(v0, off, 64);
            v1 += __shfl_down(v1, off, 64);
            v2 += __shfl_down(v2, off, 64);
            v3 += __shfl_down(v3, off, 64);
            v4 += __shfl_down(v4, off, 64);
        }
        int choice = 0; float ssq = 0.0f;
        if (lane == 0) {
            float d1 = fmaf(-2.0f, v1, v0 + v3);
            float d2 = fmaf(-2.0f, v2, v0 + v4);
            choice = (d2 < d1 || (d2 == d1 && c2 < c1)) ? 1 : 0;
            ssq = choice ? d2 : d1;             // = |z - e*|^2
        }
        choice = __shfl(choice, 0, 64);
        float2 es; es.x = choice ? e2.x : e1.x; es.y = choice ? e2.y : e1.y;
        int cs = choice ? c2 : c1;
        ((float2*)(zq + (size_t)row * DD))[lane] = es;
        if (lane == 0) {
            wsum += sqrtf(fmaxf(ssq, 0.0f));
            idsf[row] = (float)cs;
        }
    }
    __shared__ float bs[4];
    if (lane == 0) bs[w] = wsum;
    __syncthreads();
    if (t == 0)
        atomicAdd(loss, (bs[0] + bs[1] + bs[2] + bs[3]) * ((1.0f + BETA) / (float)MTOT));
}

// ---------------- launcher --------------------------------------------------
extern "C" void kernel_launch(void* const* d_in, const int* in_sizes, int n_in,
                              void* d_out, int out_size, void* d_ws, size_t ws_size,
                              hipStream_t stream) {
    const float* z = (const float*)d_in[0];
    const float* e = (const float*)d_in[1];
    float* out  = (float*)d_out;
    float* zq   = out;                          // [MTOT*DD]
    float* sim  = out + (size_t)MTOT * DD;      // [MTOT*KK]
    float* idsf = sim + (size_t)MTOT * KK;      // [MTOT]
    float* loss = idsf + MTOT;                  // [1]

    // codebook bf16 hi/lo + norms parked in z_q region (only k_finish writes z_q)
    ushort* bpre = (ushort*)zq;                 // hi: [0,262144)B, lo: [262144,524288)B
    float*  nef  = zq + 131072;                 // after both parts
    float*  inef = nef + 1024;

    k_norms <<<4,         256, 0, stream>>>(e, bpre, nef, inef, loss);
    k_prep  <<<MTOT / 32, 256, 0, stream>>>(z, sim);
    k_main  <<<MTOT / TM, 256, 0, stream>>>(sim, sim, bpre, nef, inef, (unsigned*)idsf);
    k_finish<<<MTOT / 64, 256, 0, stream>>>(z, e, zq, idsf, loss);
}